// Round 5
// baseline (46.702 us; speedup 1.0000x reference)
//
#include <hip/hip_runtime.h>

// Conv2D 3x3 pad=1: x (32,64,64,64) f32 NCHW, w (128,64,3,3) OIHW, bias(128), out (32,128,64,64) f32.
// Implicit GEMM via bf16 MFMA, barrier-free K-loop:
//   prep_x: NCHW f32 -> xT[n][h][w][ci] bf16
//   prep_w: OIHW f32 -> wA fragment-ordered bf16: wA[cb][p][c][mf][lane][8]
//           (A-fragment load = ONE coalesced global_load_dwordx4, L1/L2-resident)
//   conv_mfma4: 256 thr (4 waves), tile 64co x 4h x 64w. LDS = X only (50.7KB,
//     XOR-swizzled) -> 3 blocks/CU, 12 waves/CU. ONE barrier after X-stage, then
//     288 MFMAs + 72 ds_read_b128 + 72 coalesced L2 loads with no sync at all.

typedef short short8 __attribute__((ext_vector_type(8)));
typedef float f32x4  __attribute__((ext_vector_type(4)));

static __device__ __forceinline__ unsigned short f2bf(float f) {
    unsigned int u = __float_as_uint(f);
    u = (u + 0x7FFFu + ((u >> 16) & 1u)) >> 16;   // RNE
    return (unsigned short)u;
}
static __device__ __forceinline__ unsigned int pk2(float lo, float hi) {
    return (unsigned int)f2bf(lo) | ((unsigned int)f2bf(hi) << 16);
}

// ---------------- prep_x: x[n][ci][h][w] f32 -> xT[n][h][w][ci] bf16 ----------------
__global__ __launch_bounds__(256)
void prep_x(const float* __restrict__ x, unsigned short* __restrict__ xT)
{
    __shared__ float T[64][65];
    const int h = blockIdx.x, n = blockIdx.y, tid = threadIdx.x;
    const size_t nbase = (size_t)n * 262144 + (size_t)h * 64;
    #pragma unroll
    for (int i = 0; i < 16; ++i) {
        int idx = tid + i * 256;           // ci*64 + w
        int ci = idx >> 6, w = idx & 63;
        T[ci][w] = x[nbase + (size_t)ci * 4096 + w];
    }
    __syncthreads();
    const int w = tid >> 2, cg = tid & 3;  // cg: ci group of 16
    unsigned int pk[8];
    #pragma unroll
    for (int k = 0; k < 8; ++k)
        pk[k] = pk2(T[cg * 16 + 2 * k][w], T[cg * 16 + 2 * k + 1][w]);
    unsigned short* dst = xT + (((size_t)n * 64 + h) * 64 + w) * 64 + cg * 16;
    uint4 a; a.x = pk[0]; a.y = pk[1]; a.z = pk[2]; a.w = pk[3];
    uint4 b; b.x = pk[4]; b.y = pk[5]; b.z = pk[6]; b.w = pk[7];
    *(uint4*)(dst)     = a;
    *(uint4*)(dst + 8) = b;
}

// ------- prep_w: w[co][ci][3][3] f32 -> wA fragment order -------
// wA flat index t = ((((cb*9 + p)*2 + c)*4 + mf)*64 + lane)*8 + j
//   co = cb*64 + mf*16 + (lane&15),  ci = c*32 + (lane>>4)*8 + j
__global__ __launch_bounds__(256)
void prep_w(const float* __restrict__ w, unsigned short* __restrict__ wA)
{
    int t = blockIdx.x * 256 + threadIdx.x;
    if (t >= 73728) return;
    int j    = t & 7;
    int lane = (t >> 3) & 63;
    int mf   = (t >> 9) & 3;
    int c    = (t >> 11) & 1;
    int rest = t >> 12;            // 0..17
    int p    = rest % 9;
    int cb   = rest / 9;
    int co = cb * 64 + mf * 16 + (lane & 15);
    int ci = c * 32 + (lane >> 4) * 8 + j;
    wA[t] = f2bf(w[(size_t)(co * 64 + ci) * 9 + p]);
}

// ---------------- main MFMA conv (barrier-free K-loop) ----------------
__global__ __launch_bounds__(256, 3)
void conv_mfma4(const unsigned short* __restrict__ xT,
                const unsigned short* __restrict__ wA,
                const float* __restrict__ bias,
                float* __restrict__ out)
{
    __shared__ __align__(16) char lds[50688];   // 6 rows * 66 wp * 64 ci * 2B

    const int tid  = threadIdx.x;
    const int cb   = blockIdx.x;        // co half (0..1)
    const int h0   = blockIdx.y * 4;
    const int n    = blockIdx.z;
    const int wrow = tid >> 6;          // wave id = h row within tile (0..3)
    const int lane = tid & 63;
    const int l15  = lane & 15, l4 = lane >> 4;

    const unsigned short* xTn = xT + (size_t)n * 262144;
    const unsigned short* wAb = wA + (size_t)cb * 36864;

    // ---- bias preload ----
    f32x4 breg[4];
    #pragma unroll
    for (int mf = 0; mf < 4; ++mf)
        breg[mf] = *(const f32x4*)(bias + cb * 64 + mf * 16 + l4 * 4);

    // ---- X stage: 3168 granules of 16B (6 rows x 66 wp x 8 g), XOR-swizzled ----
    {
        uint4 xreg[13];
        #pragma unroll
        for (int k = 0; k < 13; ++k) {
            int G = tid + k * 256;
            if (k < 12 || tid < 96) {
                int hp = G / 528, rem = G - hp * 528;
                int wp = rem >> 3, g = rem & 7;
                int gh = h0 + hp - 1, gw = wp - 1;
                uint4 v; v.x = v.y = v.z = v.w = 0u;
                if ((unsigned)gh < 64u && (unsigned)gw < 64u)
                    v = *(const uint4*)(xTn + ((gh * 64 + gw) * 64 + g * 8));
                xreg[k] = v;
            }
        }
        #pragma unroll
        for (int k = 0; k < 13; ++k) {
            int G = tid + k * 256;
            if (k < 12 || tid < 96) {
                int hp = G / 528, rem = G - hp * 528;
                int wp = rem >> 3, g = rem & 7;
                *(uint4*)(lds + (hp * 66 + wp) * 128 + ((g ^ (wp & 7)) * 16)) = xreg[k];
            }
        }
    }
    __syncthreads();   // the ONLY barrier

    f32x4 acc[4][4];
    #pragma unroll
    for (int mf = 0; mf < 4; ++mf)
        #pragma unroll
        for (int nf = 0; nf < 4; ++nf)
            acc[mf][nf] = (f32x4)0.0f;

    #pragma unroll
    for (int p = 0; p < 9; ++p) {
        const int kh = p / 3, kw = p - kh * 3;
        #pragma unroll
        for (int c = 0; c < 2; ++c) {
            short8 Af[4], Bf[4];
            #pragma unroll
            for (int mf = 0; mf < 4; ++mf)
                Af[mf] = *(const short8*)(wAb + ((((p * 2 + c) * 4 + mf) * 64 + lane) << 3));
            #pragma unroll
            for (int nf = 0; nf < 4; ++nf) {
                const int hp = wrow + kh;
                const int wp = nf * 16 + l15 + kw;
                Bf[nf] = *(const short8*)(lds + (hp * 66 + wp) * 128 + (((c * 4 + l4) ^ (wp & 7)) * 16));
            }
            #pragma unroll
            for (int mf = 0; mf < 4; ++mf)
                #pragma unroll
                for (int nf = 0; nf < 4; ++nf)
                    acc[mf][nf] = __builtin_amdgcn_mfma_f32_16x16x32_bf16(
                        Af[mf], Bf[nf], acc[mf][nf], 0, 0, 0);
        }
    }

    // ---- epilogue: bias + store (C/D: col=lane&15, row=(lane>>4)*4+reg) ----
    {
        const int h = h0 + wrow;
        #pragma unroll
        for (int mf = 0; mf < 4; ++mf) {
            #pragma unroll
            for (int r = 0; r < 4; ++r) {
                const int co = cb * 64 + mf * 16 + l4 * 4 + r;
                float* orow = out + (((size_t)n * 128 + co) * 64 + h) * 64;
                const float bv = breg[mf][r];
                #pragma unroll
                for (int nf = 0; nf < 4; ++nf)
                    orow[nf * 16 + l15] = acc[mf][nf][r] + bv;
            }
        }
    }
}

// ---------------- fp32 fallback if ws too small ----------------
__global__ __launch_bounds__(256, 4)
void conv2d_f32_tiled(const float* __restrict__ x,
                      const float* __restrict__ wgt,
                      const float* __restrict__ bias,
                      float* __restrict__ out)
{
    __shared__ float Xlds[8][10][66];
    __shared__ float Wlds[32][72];
    const int tid = threadIdx.x;
    const int co0 = blockIdx.x * 32, h0 = blockIdx.y * 8, n = blockIdx.z;
    const int tco = tid >> 6, lane = tid & 63;
    float acc[8][8];
    #pragma unroll
    for (int i = 0; i < 8; ++i)
        #pragma unroll
        for (int j = 0; j < 8; ++j) acc[i][j] = 0.0f;
    for (int cc = 0; cc < 8; ++cc) {
        const int ci0 = cc * 8;
        for (int idx = tid; idx < 8 * 10 * 66; idx += 256) {
            const int ww = idx % 66, t = idx / 66, hh = t % 10, ci = t / 10;
            const int gh = h0 + hh - 1, gw = ww - 1;
            float v = 0.0f;
            if ((unsigned)gh < 64u && (unsigned)gw < 64u)
                v = x[(((size_t)n * 64 + ci0 + ci) * 64 + gh) * 64 + gw];
            Xlds[ci][hh][ww] = v;
        }
        for (int idx = tid; idx < 32 * 72; idx += 256) {
            const int r = idx % 72, co = idx / 72;
            Wlds[co][r] = wgt[(size_t)(co0 + co) * 576 + ci0 * 9 + r];
        }
        __syncthreads();
        for (int ci = 0; ci < 8; ++ci)
            #pragma unroll
            for (int kh = 0; kh < 3; ++kh)
                #pragma unroll
                for (int kw = 0; kw < 3; ++kw) {
                    float wv[8];
                    #pragma unroll
                    for (int i = 0; i < 8; ++i) wv[i] = Wlds[tco * 8 + i][ci * 9 + kh * 3 + kw];
                    #pragma unroll
                    for (int j = 0; j < 8; ++j) {
                        const float xv = Xlds[ci][j + kh][lane + kw];
                        #pragma unroll
                        for (int i = 0; i < 8; ++i) acc[i][j] = fmaf(wv[i], xv, acc[i][j]);
                    }
                }
        __syncthreads();
    }
    #pragma unroll
    for (int i = 0; i < 8; ++i) {
        const int co = co0 + tco * 8 + i;
        const float b = bias[co];
        #pragma unroll
        for (int j = 0; j < 8; ++j)
            out[(((size_t)n * 128 + co) * 64 + (h0 + j)) * 64 + lane] = acc[i][j] + b;
    }
}

extern "C" void kernel_launch(void* const* d_in, const int* in_sizes, int n_in,
                              void* d_out, int out_size, void* d_ws, size_t ws_size,
                              hipStream_t stream)
{
    const float* x    = (const float*)d_in[0];
    const float* wgt  = (const float*)d_in[1];
    const float* bias = (const float*)d_in[2];
    float* out        = (float*)d_out;

    const size_t XT_BYTES = (size_t)32 * 64 * 64 * 64 * 2;   // 33554432
    const size_t WT_BYTES = (size_t)128 * 576 * 2;           // 147456

    if (ws_size < XT_BYTES + WT_BYTES) {
        dim3 grid(4, 8, 32);
        conv2d_f32_tiled<<<grid, 256, 0, stream>>>(x, wgt, bias, out);
        return;
    }

    unsigned short* xT = (unsigned short*)d_ws;
    unsigned short* wA = (unsigned short*)((char*)d_ws + XT_BYTES);

    prep_x<<<dim3(64, 32), 256, 0, stream>>>(x, xT);
    prep_w<<<dim3((73728 + 255) / 256), 256, 0, stream>>>(wgt, wA);
    conv_mfma4<<<dim3(2, 16, 32), 256, 0, stream>>>(xT, wA, bias, out);
}

// Round 6
// 42.712 us; speedup vs baseline: 1.0934x; 1.0934x over previous
//
#include <hip/hip_runtime.h>

// Conv2D 3x3 pad=1: x (32,64,64,64) f32 NCHW, w (128,64,3,3) OIHW, bias(128), out (32,128,64,64) f32.
// Implicit GEMM via bf16 MFMA, barrier-free K-loop, occupancy-tuned:
//   prep_x: NCHW f32 -> xT[n][h][w][ci] bf16
//   prep_w: OIHW f32 -> wA fragment-ordered bf16 (A-frag = ONE coalesced 1KB load)
//   conv_mfma5: 512 thr (8 waves = 2 cb x 4 h rows) share one 50.7KB X tile.
//     launch_bounds(512,4) pins regs <=128 (incl AGPR acc) -> 4 waves/SIMD.
//     Single barrier after X-stage; K-loop: 4 global A-frag loads + 4 ds_read_b128
//     + 16 MFMA per c-iter, s_setprio around the MFMA cluster. Bias loaded in epilogue.

typedef short short8 __attribute__((ext_vector_type(8)));
typedef float f32x4  __attribute__((ext_vector_type(4)));

static __device__ __forceinline__ unsigned short f2bf(float f) {
    unsigned int u = __float_as_uint(f);
    u = (u + 0x7FFFu + ((u >> 16) & 1u)) >> 16;   // RNE
    return (unsigned short)u;
}
static __device__ __forceinline__ unsigned int pk2(float lo, float hi) {
    return (unsigned int)f2bf(lo) | ((unsigned int)f2bf(hi) << 16);
}

// ---------------- prep_x: x[n][ci][h][w] f32 -> xT[n][h][w][ci] bf16 ----------------
__global__ __launch_bounds__(256)
void prep_x(const float* __restrict__ x, unsigned short* __restrict__ xT)
{
    __shared__ float T[64][65];
    const int h = blockIdx.x, n = blockIdx.y, tid = threadIdx.x;
    const size_t nbase = (size_t)n * 262144 + (size_t)h * 64;
    #pragma unroll
    for (int i = 0; i < 16; ++i) {
        int idx = tid + i * 256;           // ci*64 + w
        int ci = idx >> 6, w = idx & 63;
        T[ci][w] = x[nbase + (size_t)ci * 4096 + w];
    }
    __syncthreads();
    const int w = tid >> 2, cg = tid & 3;  // cg: ci group of 16
    unsigned int pk[8];
    #pragma unroll
    for (int k = 0; k < 8; ++k)
        pk[k] = pk2(T[cg * 16 + 2 * k][w], T[cg * 16 + 2 * k + 1][w]);
    unsigned short* dst = xT + (((size_t)n * 64 + h) * 64 + w) * 64 + cg * 16;
    uint4 a; a.x = pk[0]; a.y = pk[1]; a.z = pk[2]; a.w = pk[3];
    uint4 b; b.x = pk[4]; b.y = pk[5]; b.z = pk[6]; b.w = pk[7];
    *(uint4*)(dst)     = a;
    *(uint4*)(dst + 8) = b;
}

// ------- prep_w: w[co][ci][3][3] f32 -> wA fragment order -------
// wA flat index t = ((((cb*9 + p)*2 + c)*4 + mf)*64 + lane)*8 + j
//   co = cb*64 + mf*16 + (lane&15),  ci = c*32 + (lane>>4)*8 + j
__global__ __launch_bounds__(256)
void prep_w(const float* __restrict__ w, unsigned short* __restrict__ wA)
{
    int t = blockIdx.x * 256 + threadIdx.x;
    if (t >= 73728) return;
    int j    = t & 7;
    int lane = (t >> 3) & 63;
    int mf   = (t >> 9) & 3;
    int c    = (t >> 11) & 1;
    int rest = t >> 12;            // 0..17
    int p    = rest % 9;
    int cb   = rest / 9;
    int co = cb * 64 + mf * 16 + (lane & 15);
    int ci = c * 32 + (lane >> 4) * 8 + j;
    wA[t] = f2bf(w[(size_t)(co * 64 + ci) * 9 + p]);
}

// ---------------- main MFMA conv (8 waves, 4 waves/SIMD) ----------------
__global__ __launch_bounds__(512, 4)
void conv_mfma5(const unsigned short* __restrict__ xT,
                const unsigned short* __restrict__ wA,
                const float* __restrict__ bias,
                float* __restrict__ out)
{
    __shared__ __align__(16) char lds[50688];   // 6 rows * 66 wp * 64 ci * 2B

    const int tid  = threadIdx.x;
    const int h0   = blockIdx.x * 4;
    const int n    = blockIdx.y;
    const int wid  = tid >> 6;          // 0..7
    const int cb   = wid >> 2;          // co half (0..1)
    const int wrow = wid & 3;           // h row within tile
    const int lane = tid & 63;
    const int l15  = lane & 15, l4 = lane >> 4;

    const unsigned short* xTn = xT + (size_t)n * 262144;
    const unsigned short* wAb = wA + (size_t)cb * 36864;

    // ---- X stage: 3168 granules of 16B (6 rows x 66 wp x 8 g), XOR-swizzled ----
    {
        uint4 xreg[7];
        #pragma unroll
        for (int k = 0; k < 7; ++k) {
            int G = tid + k * 512;
            if (k < 6 || tid < 96) {
                int hp = G / 528, rem = G - hp * 528;
                int wp = rem >> 3, g = rem & 7;
                int gh = h0 + hp - 1, gw = wp - 1;
                uint4 v; v.x = v.y = v.z = v.w = 0u;
                if ((unsigned)gh < 64u && (unsigned)gw < 64u)
                    v = *(const uint4*)(xTn + ((gh * 64 + gw) * 64 + g * 8));
                xreg[k] = v;
            }
        }
        #pragma unroll
        for (int k = 0; k < 7; ++k) {
            int G = tid + k * 512;
            if (k < 6 || tid < 96) {
                int hp = G / 528, rem = G - hp * 528;
                int wp = rem >> 3, g = rem & 7;
                *(uint4*)(lds + (hp * 66 + wp) * 128 + ((g ^ (wp & 7)) * 16)) = xreg[k];
            }
        }
    }
    __syncthreads();   // the ONLY barrier

    f32x4 acc[4][4];
    #pragma unroll
    for (int mf = 0; mf < 4; ++mf)
        #pragma unroll
        for (int nf = 0; nf < 4; ++nf)
            acc[mf][nf] = (f32x4)0.0f;

    #pragma unroll
    for (int p = 0; p < 9; ++p) {
        const int kh = p / 3, kw = p - kh * 3;
        #pragma unroll
        for (int c = 0; c < 2; ++c) {
            short8 Af[4], Bf[4];
            #pragma unroll
            for (int mf = 0; mf < 4; ++mf)
                Af[mf] = *(const short8*)(wAb + ((((p * 2 + c) * 4 + mf) * 64 + lane) << 3));
            #pragma unroll
            for (int nf = 0; nf < 4; ++nf) {
                const int hp = wrow + kh;
                const int wp = nf * 16 + l15 + kw;
                Bf[nf] = *(const short8*)(lds + (hp * 66 + wp) * 128 + (((c * 4 + l4) ^ (wp & 7)) * 16));
            }
            __builtin_amdgcn_s_setprio(1);
            #pragma unroll
            for (int mf = 0; mf < 4; ++mf)
                #pragma unroll
                for (int nf = 0; nf < 4; ++nf)
                    acc[mf][nf] = __builtin_amdgcn_mfma_f32_16x16x32_bf16(
                        Af[mf], Bf[nf], acc[mf][nf], 0, 0, 0);
            __builtin_amdgcn_s_setprio(0);
        }
    }

    // ---- epilogue: bias (loaded here, not held) + store ----
    {
        const int h = h0 + wrow;
        #pragma unroll
        for (int mf = 0; mf < 4; ++mf) {
            const f32x4 bv4 = *(const f32x4*)(bias + cb * 64 + mf * 16 + l4 * 4);
            #pragma unroll
            for (int r = 0; r < 4; ++r) {
                const int co = cb * 64 + mf * 16 + l4 * 4 + r;
                float* orow = out + (((size_t)n * 128 + co) * 64 + h) * 64;
                const float bv = bv4[r];
                #pragma unroll
                for (int nf = 0; nf < 4; ++nf)
                    orow[nf * 16 + l15] = acc[mf][nf][r] + bv;
            }
        }
    }
}

// ---------------- fp32 fallback if ws too small ----------------
__global__ __launch_bounds__(256, 4)
void conv2d_f32_tiled(const float* __restrict__ x,
                      const float* __restrict__ wgt,
                      const float* __restrict__ bias,
                      float* __restrict__ out)
{
    __shared__ float Xlds[8][10][66];
    __shared__ float Wlds[32][72];
    const int tid = threadIdx.x;
    const int co0 = blockIdx.x * 32, h0 = blockIdx.y * 8, n = blockIdx.z;
    const int tco = tid >> 6, lane = tid & 63;
    float acc[8][8];
    #pragma unroll
    for (int i = 0; i < 8; ++i)
        #pragma unroll
        for (int j = 0; j < 8; ++j) acc[i][j] = 0.0f;
    for (int cc = 0; cc < 8; ++cc) {
        const int ci0 = cc * 8;
        for (int idx = tid; idx < 8 * 10 * 66; idx += 256) {
            const int ww = idx % 66, t = idx / 66, hh = t % 10, ci = t / 10;
            const int gh = h0 + hh - 1, gw = ww - 1;
            float v = 0.0f;
            if ((unsigned)gh < 64u && (unsigned)gw < 64u)
                v = x[(((size_t)n * 64 + ci0 + ci) * 64 + gh) * 64 + gw];
            Xlds[ci][hh][ww] = v;
        }
        for (int idx = tid; idx < 32 * 72; idx += 256) {
            const int r = idx % 72, co = idx / 72;
            Wlds[co][r] = wgt[(size_t)(co0 + co) * 576 + ci0 * 9 + r];
        }
        __syncthreads();
        for (int ci = 0; ci < 8; ++ci)
            #pragma unroll
            for (int kh = 0; kh < 3; ++kh)
                #pragma unroll
                for (int kw = 0; kw < 3; ++kw) {
                    float wv[8];
                    #pragma unroll
                    for (int i = 0; i < 8; ++i) wv[i] = Wlds[tco * 8 + i][ci * 9 + kh * 3 + kw];
                    #pragma unroll
                    for (int j = 0; j < 8; ++j) {
                        const float xv = Xlds[ci][j + kh][lane + kw];
                        #pragma unroll
                        for (int i = 0; i < 8; ++i) acc[i][j] = fmaf(wv[i], xv, acc[i][j]);
                    }
                }
        __syncthreads();
    }
    #pragma unroll
    for (int i = 0; i < 8; ++i) {
        const int co = co0 + tco * 8 + i;
        const float b = bias[co];
        #pragma unroll
        for (int j = 0; j < 8; ++j)
            out[(((size_t)n * 128 + co) * 64 + (h0 + j)) * 64 + lane] = acc[i][j] + b;
    }
}

extern "C" void kernel_launch(void* const* d_in, const int* in_sizes, int n_in,
                              void* d_out, int out_size, void* d_ws, size_t ws_size,
                              hipStream_t stream)
{
    const float* x    = (const float*)d_in[0];
    const float* wgt  = (const float*)d_in[1];
    const float* bias = (const float*)d_in[2];
    float* out        = (float*)d_out;

    const size_t XT_BYTES = (size_t)32 * 64 * 64 * 64 * 2;   // 33554432
    const size_t WT_BYTES = (size_t)128 * 576 * 2;           // 147456

    if (ws_size < XT_BYTES + WT_BYTES) {
        dim3 grid(4, 8, 32);
        conv2d_f32_tiled<<<grid, 256, 0, stream>>>(x, wgt, bias, out);
        return;
    }

    unsigned short* xT = (unsigned short*)d_ws;
    unsigned short* wA = (unsigned short*)((char*)d_ws + XT_BYTES);

    prep_x<<<dim3(64, 32), 256, 0, stream>>>(x, xT);
    prep_w<<<dim3((73728 + 255) / 256), 256, 0, stream>>>(wgt, wA);
    conv_mfma5<<<dim3(16, 32), 512, 0, stream>>>(xT, wA, bias, out);
}